// Round 1
// baseline (801.061 us; speedup 1.0000x reference)
//
#include <hip/hip_runtime.h>
#include <stdint.h>

// Problem constants (fixed by setup_inputs)
#define CCH 64
#define HW  (1024 * 1024)
#define NPIX (1024 * 1024)
#define NSEG 4096
#define NBIN 65536          // pos >> 4 buckets (one 64B feature line per bucket)

#define SLABS 16            // channel slabs, CPS channels each
#define CPS 4               // channels per slab -> 4096*4*4B = 64 KB LDS accumulators
#define RANGES 16           // sorted-entry ranges
#define EPR (NPIX / RANGES) // 65536 entries per range

// ws layout (KB offsets):
//      0  packed        u32[NPIX]              4096 KB
//   4096  sortedPos     u32[NPIX]              4096 KB
//   8192  poshist       u32[NBIN]               256 KB  \ one contiguous 512 KB memset
//   8448  seghistPad    u32[NSEG*16]            256 KB  /
//   8704  posLocal      u32[NBIN]               256 KB
//   8960  posBlk        u32[64]                   4 KB
//   9216  posCursorPad  u32[NBIN*16]           4096 KB
//  13312  partials      f32[RANGES*SLABS*16384] 16384 KB
//  29696  end
#define WS_NEED ((size_t)29696 * 1024)

// 2 entries per thread
__global__ void k1_pack_hist(const int4* __restrict__ pix2,
                             const int2* __restrict__ seg2,
                             uint2* __restrict__ packed2,
                             uint32_t* __restrict__ poshist,
                             uint32_t* __restrict__ seghistPad) {
    int n = blockIdx.x * blockDim.x + threadIdx.x;
    int4 yx = pix2[n];                    // (y0,x0,y1,x1)
    int2 ss = seg2[n];
    uint32_t pos0 = ((uint32_t)yx.x << 10) | (uint32_t)yx.y;
    uint32_t pos1 = ((uint32_t)yx.z << 10) | (uint32_t)yx.w;
    packed2[n] = make_uint2(((uint32_t)ss.x << 20) | pos0,
                            ((uint32_t)ss.y << 20) | pos1);
    atomicAdd(&poshist[pos0 >> 4], 1u);
    atomicAdd(&poshist[pos1 >> 4], 1u);
    atomicAdd(&seghistPad[(uint32_t)ss.x * 16], 1u);
    atomicAdd(&seghistPad[(uint32_t)ss.y * 16], 1u);
}

// 64 blocks x 1024: local inclusive scan of poshist -> local EXCLUSIVE + block total
__global__ void k2a_scan_local(const uint32_t* __restrict__ poshist,
                               uint32_t* __restrict__ posLocal,
                               uint32_t* __restrict__ posBlk) {
    __shared__ uint32_t sh[1024];
    int t = threadIdx.x, b = blockIdx.x;
    int i = b * 1024 + t;
    uint32_t v = poshist[i];
    sh[t] = v;
    __syncthreads();
    for (int off = 1; off < 1024; off <<= 1) {
        uint32_t u = (t >= off) ? sh[t - off] : 0u;
        __syncthreads();
        sh[t] += u;
        __syncthreads();
    }
    uint32_t inc = sh[t];
    posLocal[i] = inc - v;
    if (t == 1023) posBlk[b] = inc;
}

// 64 blocks x 1024: each block reduces posBlk[0..b) itself (replaces old k2b+k2c),
// then final cursor = local exclusive + block base, 1 bin / 64B line
__global__ void k2c_scan_add(const uint32_t* __restrict__ posLocal,
                             const uint32_t* __restrict__ posBlk,
                             uint32_t* __restrict__ posCursorPad) {
    __shared__ uint32_t sbase;
    int t = threadIdx.x, b = blockIdx.x;
    if (t < 64) {                                // wave 0
        uint32_t v = (t < b) ? posBlk[t] : 0u;
        for (int off = 32; off; off >>= 1) v += __shfl_down(v, off);
        if (t == 0) sbase = v;
    }
    __syncthreads();
    int i = b * 1024 + t;
    posCursorPad[(size_t)i * 16] = posLocal[i] + sbase;
}

// 2 entries per thread
__global__ void k3_scatter(const uint2* __restrict__ packed2,
                           uint32_t* __restrict__ posCursorPad,
                           uint32_t* __restrict__ sorted) {
    int n = blockIdx.x * blockDim.x + threadIdx.x;
    uint2 p = packed2[n];
    uint32_t d0 = atomicAdd(&posCursorPad[(size_t)((p.x & 0xFFFFFu) >> 4) * 16], 1u);
    uint32_t d1 = atomicAdd(&posCursorPad[(size_t)((p.y & 0xFFFFFu) >> 4) * 16], 1u);
    sorted[d0] = p.x;
    sorted[d1] = p.y;
}

// Main accumulate. Block = (range, slab): stream 64K position-sorted entries,
// read CPS feature planes coalesced (nontemporal: each feat line is touched by
// exactly one block, once), fire-and-forget ds_add_f32 into LDS segment
// accumulators (seg ^ (j<<2) XOR keeps per-j rows off the same banks),
// then flush one coalesced 64 KB partial.
__global__ __launch_bounds__(1024) void k4_accum(const float* __restrict__ feat,
                                                 const uint32_t* __restrict__ sorted,
                                                 float* __restrict__ partials) {
    __shared__ float sums[CPS * NSEG];           // 64 KB
    const int tid = threadIdx.x;
    const int range = blockIdx.x >> 4;           // consecutive blocks share a range's
    const int slab  = blockIdx.x & 15;           // sorted[] slice -> L2 reuse
    for (int i = tid; i < CPS * NSEG; i += 1024) sums[i] = 0.f;

    const uint2* sp = (const uint2*)(sorted + (size_t)range * EPR);   // 32768 uint2
    const float* fbase = feat + (size_t)(slab * CPS) * HW;
    __syncthreads();

    uint2 pk = sp[tid];                          // software prefetch: pk[it+1]
    for (int it = 0; it < 32; ++it) {            // overlaps feat loads of pk[it]
        uint2 cur = pk;
        if (it < 31) pk = sp[(it + 1) * 1024 + tid];
        uint32_t pos0 = cur.x & 0xFFFFFu, seg0 = cur.x >> 20;
        uint32_t pos1 = cur.y & 0xFFFFFu, seg1 = cur.y >> 20;
#pragma unroll
        for (int j = 0; j < CPS; ++j) {
            float v0 = __builtin_nontemporal_load(&fbase[(size_t)j * HW + pos0]);
            float v1 = __builtin_nontemporal_load(&fbase[(size_t)j * HW + pos1]);
            __hip_atomic_fetch_add(&sums[j * NSEG + (seg0 ^ (j << 2))], v0,
                                   __ATOMIC_RELAXED, __HIP_MEMORY_SCOPE_WORKGROUP);
            __hip_atomic_fetch_add(&sums[j * NSEG + (seg1 ^ (j << 2))], v1,
                                   __ATOMIC_RELAXED, __HIP_MEMORY_SCOPE_WORKGROUP);
        }
    }
    __syncthreads();

    float* pb = partials + ((size_t)(range * SLABS + slab)) * (CPS * NSEG);
    for (int i = tid; i < CPS * NSEG; i += 1024) {
        int j = i & 3, seg = i >> 2;
        pb[i] = sums[j * NSEG + (seg ^ (j << 2))];
    }
}

// Sum the 16 range-copies (coalesced: 16 strided-256KB streams) + divide by count.
__global__ __launch_bounds__(256) void k5_red(const float* __restrict__ partials,
                                              const uint32_t* __restrict__ seghistPad,
                                              float* __restrict__ out) {
    int g = blockIdx.x * 256 + threadIdx.x;      // 0 .. 262143
    int slab = g >> 14;                          // 16384 values per slab
    int w = g & 16383;                           // w = seg*4 + j
    float s = 0.f;
#pragma unroll
    for (int r = 0; r < RANGES; ++r)
        s += partials[(((size_t)(r * SLABS + slab)) << 14) + w];
    int seg = w >> 2, j = w & 3;
    uint32_t cnt = seghistPad[seg * 16];
    out[seg * 64 + slab * 4 + j] = s / (float)(cnt ? cnt : 1u);
}

extern "C" void kernel_launch(void* const* d_in, const int* in_sizes, int n_in,
                              void* d_out, int out_size, void* d_ws, size_t ws_size,
                              hipStream_t stream) {
    const float* feat = (const float*)d_in[0];
    const int*   pix  = (const int*)d_in[1];
    const int*   seg  = (const int*)d_in[2];
    float* out = (float*)d_out;

    uint8_t* ws = (uint8_t*)d_ws;
    uint32_t* packed       = (uint32_t*)(ws);
    uint32_t* sortedPos    = (uint32_t*)(ws + (size_t)4096 * 1024);
    uint32_t* poshist      = (uint32_t*)(ws + (size_t)8192 * 1024);
    uint32_t* seghistPad   = (uint32_t*)(ws + (size_t)8448 * 1024);
    uint32_t* posLocal     = (uint32_t*)(ws + (size_t)8704 * 1024);
    uint32_t* posBlk       = (uint32_t*)(ws + (size_t)8960 * 1024);
    uint32_t* posCursorPad = (uint32_t*)(ws + (size_t)9216 * 1024);
    float*    partials     = (float*)   (ws + (size_t)13312 * 1024);

    hipMemsetAsync(poshist, 0, (size_t)512 * 1024, stream);   // poshist + seghistPad

    k1_pack_hist<<<NPIX / 512, 256, 0, stream>>>((const int4*)pix, (const int2*)seg,
                                                 (uint2*)packed, poshist, seghistPad);
    k2a_scan_local<<<64, 1024, 0, stream>>>(poshist, posLocal, posBlk);
    k2c_scan_add<<<64, 1024, 0, stream>>>(posLocal, posBlk, posCursorPad);
    k3_scatter<<<NPIX / 512, 256, 0, stream>>>((const uint2*)packed, posCursorPad, sortedPos);
    k4_accum<<<RANGES * SLABS, 1024, 0, stream>>>(feat, sortedPos, partials);
    k5_red<<<(NSEG * CCH) / 256, 256, 0, stream>>>(partials, seghistPad, out);
}

// Round 2
// 773.519 us; speedup vs baseline: 1.0356x; 1.0356x over previous
//
#include <hip/hip_runtime.h>
#include <stdint.h>

// Problem constants (fixed by setup_inputs)
#define CCH 64
#define HW  (1024 * 1024)
#define NPIX (1024 * 1024)
#define NSEG 4096
#define NBIN 65536          // pos >> 4 buckets (one 64B feature line per bucket)

#define SLABS 16            // channel slabs, CPS channels each
#define CPS 4               // channels per slab -> 4096*4*4B = 64 KB LDS accumulators
#define RANGES 32           // sorted-entry ranges (32 -> 512 blocks -> 2 blocks/CU)
#define EPR (NPIX / RANGES) // 32768 entries per range
#define NIT (EPR / 2048)    // 16 iterations (2 entries/thread, 1024 threads)

// ws layout (KB offsets):
//      0  packed        u32[NPIX]              4096 KB
//   4096  sortedPos     u32[NPIX]              4096 KB
//   8192  poshist       u32[NBIN]               256 KB  \ one contiguous 512 KB memset
//   8448  seghistPad    u32[NSEG*16]            256 KB  /
//   8704  posLocal      u32[NBIN]               256 KB
//   8960  posBlk        u32[64]                   4 KB
//   9216  posCursorPad  u32[NBIN*16]           4096 KB
//  13312  partials      f32[RANGES*SLABS*16384] 32768 KB
//  46080  end
#define WS_NEED ((size_t)46080 * 1024)

// 2 entries per thread
__global__ void k1_pack_hist(const int4* __restrict__ pix2,
                             const int2* __restrict__ seg2,
                             uint2* __restrict__ packed2,
                             uint32_t* __restrict__ poshist,
                             uint32_t* __restrict__ seghistPad) {
    int n = blockIdx.x * blockDim.x + threadIdx.x;
    int4 yx = pix2[n];                    // (y0,x0,y1,x1)
    int2 ss = seg2[n];
    uint32_t pos0 = ((uint32_t)yx.x << 10) | (uint32_t)yx.y;
    uint32_t pos1 = ((uint32_t)yx.z << 10) | (uint32_t)yx.w;
    packed2[n] = make_uint2(((uint32_t)ss.x << 20) | pos0,
                            ((uint32_t)ss.y << 20) | pos1);
    atomicAdd(&poshist[pos0 >> 4], 1u);
    atomicAdd(&poshist[pos1 >> 4], 1u);
    atomicAdd(&seghistPad[(uint32_t)ss.x * 16], 1u);
    atomicAdd(&seghistPad[(uint32_t)ss.y * 16], 1u);
}

// 64 blocks x 1024: local inclusive scan of poshist -> local EXCLUSIVE + block total
__global__ void k2a_scan_local(const uint32_t* __restrict__ poshist,
                               uint32_t* __restrict__ posLocal,
                               uint32_t* __restrict__ posBlk) {
    __shared__ uint32_t sh[1024];
    int t = threadIdx.x, b = blockIdx.x;
    int i = b * 1024 + t;
    uint32_t v = poshist[i];
    sh[t] = v;
    __syncthreads();
    for (int off = 1; off < 1024; off <<= 1) {
        uint32_t u = (t >= off) ? sh[t - off] : 0u;
        __syncthreads();
        sh[t] += u;
        __syncthreads();
    }
    uint32_t inc = sh[t];
    posLocal[i] = inc - v;
    if (t == 1023) posBlk[b] = inc;
}

// 64 blocks x 1024: each block reduces posBlk[0..b) itself,
// then final cursor = local exclusive + block base, 1 bin / 64B line
__global__ void k2c_scan_add(const uint32_t* __restrict__ posLocal,
                             const uint32_t* __restrict__ posBlk,
                             uint32_t* __restrict__ posCursorPad) {
    __shared__ uint32_t sbase;
    int t = threadIdx.x, b = blockIdx.x;
    if (t < 64) {                                // wave 0
        uint32_t v = (t < b) ? posBlk[t] : 0u;
        for (int off = 32; off; off >>= 1) v += __shfl_down(v, off);
        if (t == 0) sbase = v;
    }
    __syncthreads();
    int i = b * 1024 + t;
    posCursorPad[(size_t)i * 16] = posLocal[i] + sbase;
}

// 2 entries per thread
__global__ void k3_scatter(const uint2* __restrict__ packed2,
                           uint32_t* __restrict__ posCursorPad,
                           uint32_t* __restrict__ sorted) {
    int n = blockIdx.x * blockDim.x + threadIdx.x;
    uint2 p = packed2[n];
    uint32_t d0 = atomicAdd(&posCursorPad[(size_t)((p.x & 0xFFFFFu) >> 4) * 16], 1u);
    uint32_t d1 = atomicAdd(&posCursorPad[(size_t)((p.y & 0xFFFFFu) >> 4) * 16], 1u);
    sorted[d0] = p.x;
    sorted[d1] = p.y;
}

// Main accumulate. Block = (range, slab). Software-pipelined:
//   iter it: issue sorted prefetch (it+2) and ALL 8 feat loads of entry it+1
//            into vb[] BEFORE the 8 LDS atomics of it (reading va[]).
// vmcnt completes in-order -> waiting on va (older) never drains vb (newer):
// 8+ loads stay in flight per wave at all times. 2 blocks/CU (128 KB LDS).
__global__ __launch_bounds__(1024) void k4_accum(const float* __restrict__ feat,
                                                 const uint32_t* __restrict__ sorted,
                                                 float* __restrict__ partials) {
    __shared__ float sums[CPS * NSEG];           // 64 KB
    const int tid = threadIdx.x;
    const int range = blockIdx.x >> 4;
    const int slab  = blockIdx.x & 15;
    for (int i = tid; i < CPS * NSEG; i += 1024) sums[i] = 0.f;

    const uint2* sp = (const uint2*)(sorted + (size_t)range * EPR);   // 16384 uint2
    const float* fbase = feat + (size_t)(slab * CPS) * HW;
    __syncthreads();

    uint2 e0 = sp[tid];
    uint2 e1 = sp[1024 + tid];
    float va[2 * CPS], vb[2 * CPS];
    {
        uint32_t p0 = e0.x & 0xFFFFFu, p1 = e0.y & 0xFFFFFu;
#pragma unroll
        for (int j = 0; j < CPS; ++j) {
            va[2 * j]     = fbase[(size_t)j * HW + p0];
            va[2 * j + 1] = fbase[(size_t)j * HW + p1];
        }
    }
    for (int it = 0; it < NIT; ++it) {
        uint2 e2 = sp[min(it + 2, NIT - 1) * 1024 + tid];
        if (it + 1 < NIT) {
            uint32_t p0 = e1.x & 0xFFFFFu, p1 = e1.y & 0xFFFFFu;
#pragma unroll
            for (int j = 0; j < CPS; ++j) {
                vb[2 * j]     = fbase[(size_t)j * HW + p0];
                vb[2 * j + 1] = fbase[(size_t)j * HW + p1];
            }
        }
        uint32_t s0 = e0.x >> 20, s1 = e0.y >> 20;
#pragma unroll
        for (int j = 0; j < CPS; ++j) {
            __hip_atomic_fetch_add(&sums[j * NSEG + (s0 ^ (j << 2))], va[2 * j],
                                   __ATOMIC_RELAXED, __HIP_MEMORY_SCOPE_WORKGROUP);
            __hip_atomic_fetch_add(&sums[j * NSEG + (s1 ^ (j << 2))], va[2 * j + 1],
                                   __ATOMIC_RELAXED, __HIP_MEMORY_SCOPE_WORKGROUP);
        }
        e0 = e1; e1 = e2;
#pragma unroll
        for (int k = 0; k < 2 * CPS; ++k) va[k] = vb[k];
    }
    __syncthreads();

    float* pb = partials + ((size_t)blockIdx.x) * (CPS * NSEG);
    for (int i = tid; i < CPS * NSEG; i += 1024) {
        int j = i & 3, seg = i >> 2;
        pb[i] = sums[j * NSEG + (seg ^ (j << 2))];
    }
}

// Sum the 32 range-copies (coalesced strided streams) + divide by count.
__global__ __launch_bounds__(256) void k5_red(const float* __restrict__ partials,
                                              const uint32_t* __restrict__ seghistPad,
                                              float* __restrict__ out) {
    int g = blockIdx.x * 256 + threadIdx.x;      // 0 .. 262143
    int slab = g >> 14;                          // 16384 values per slab
    int w = g & 16383;                           // w = seg*4 + j
    float s = 0.f;
#pragma unroll
    for (int r = 0; r < RANGES; ++r)
        s += partials[(((size_t)(r * SLABS + slab)) << 14) + w];
    int seg = w >> 2, j = w & 3;
    uint32_t cnt = seghistPad[seg * 16];
    out[seg * 64 + slab * 4 + j] = s / (float)(cnt ? cnt : 1u);
}

extern "C" void kernel_launch(void* const* d_in, const int* in_sizes, int n_in,
                              void* d_out, int out_size, void* d_ws, size_t ws_size,
                              hipStream_t stream) {
    const float* feat = (const float*)d_in[0];
    const int*   pix  = (const int*)d_in[1];
    const int*   seg  = (const int*)d_in[2];
    float* out = (float*)d_out;

    uint8_t* ws = (uint8_t*)d_ws;
    uint32_t* packed       = (uint32_t*)(ws);
    uint32_t* sortedPos    = (uint32_t*)(ws + (size_t)4096 * 1024);
    uint32_t* poshist      = (uint32_t*)(ws + (size_t)8192 * 1024);
    uint32_t* seghistPad   = (uint32_t*)(ws + (size_t)8448 * 1024);
    uint32_t* posLocal     = (uint32_t*)(ws + (size_t)8704 * 1024);
    uint32_t* posBlk       = (uint32_t*)(ws + (size_t)8960 * 1024);
    uint32_t* posCursorPad = (uint32_t*)(ws + (size_t)9216 * 1024);
    float*    partials     = (float*)   (ws + (size_t)13312 * 1024);

    hipMemsetAsync(poshist, 0, (size_t)512 * 1024, stream);   // poshist + seghistPad

    k1_pack_hist<<<NPIX / 512, 256, 0, stream>>>((const int4*)pix, (const int2*)seg,
                                                 (uint2*)packed, poshist, seghistPad);
    k2a_scan_local<<<64, 1024, 0, stream>>>(poshist, posLocal, posBlk);
    k2c_scan_add<<<64, 1024, 0, stream>>>(posLocal, posBlk, posCursorPad);
    k3_scatter<<<NPIX / 512, 256, 0, stream>>>((const uint2*)packed, posCursorPad, sortedPos);
    k4_accum<<<RANGES * SLABS, 1024, 0, stream>>>(feat, sortedPos, partials);
    k5_red<<<(NSEG * CCH) / 256, 256, 0, stream>>>(partials, seghistPad, out);
}